// Round 5
// baseline (378.367 us; speedup 1.0000x reference)
//
#include <hip/hip_runtime.h>
#include <hip/hip_bf16.h>

using bf16 = __hip_bfloat16;
typedef __attribute__((ext_vector_type(8))) short short8;
typedef __attribute__((ext_vector_type(4))) float f32x4;

constexpr int N   = 50000;
constexpr int E   = 800000;
constexpr int NIN = 300;
constexpr int H   = 4;
constexpr int C   = 64;
constexpr int HC  = H * C;      // 256
constexpr int G   = 256;
constexpr int NOUT = 768;
constexpr int NKB = 10;         // K blocks of 32 (K padded 300->320)
constexpr int MP  = 50048;      // M padded to 782*64

__device__ __forceinline__ float b2f(bf16 v) { return __bfloat162float(v); }
__device__ __forceinline__ float us2f(unsigned short u) {
    bf16 b; *(unsigned short*)&b = u; return __bfloat162float(b);
}
__device__ __forceinline__ unsigned short f2us(float f) {
    bf16 b = __float2bfloat16(f); return *(unsigned short*)&b;
}
__device__ __forceinline__ float lrelu_att(float v) { return v > 0.f ? v : 0.2f * v; }
__device__ __forceinline__ float lrelu_act(float v) { return v > 0.f ? v : 0.01f * v; }
__device__ __forceinline__ float ldin(const void* p, int isbf, size_t i) {
    return isbf ? b2f(((const bf16*)p)[i]) : ((const float*)p)[i];
}
__device__ __forceinline__ short8 pack8u(ushort4 lo, ushort4 hi) {
    short8 r;
    r[0] = (short)lo.x; r[1] = (short)lo.y; r[2] = (short)lo.z; r[3] = (short)lo.w;
    r[4] = (short)hi.x; r[5] = (short)hi.y; r[6] = (short)hi.z; r[7] = (short)hi.w;
    return r;
}
__device__ __forceinline__ short8 pack8f(float4 lo, float4 hi) {
    short8 r;
    r[0] = (short)f2us(lo.x); r[1] = (short)f2us(lo.y); r[2] = (short)f2us(lo.z); r[3] = (short)f2us(lo.w);
    r[4] = (short)f2us(hi.x); r[5] = (short)f2us(hi.y); r[6] = (short)f2us(hi.z); r[7] = (short)f2us(hi.w);
    return r;
}

// in-block dtype detection (reads first 256 uint16s of x; deterministic)
__device__ __forceinline__ int block_detect(const unsigned short* __restrict__ xr) {
    __shared__ int cnt_s;
    if (threadIdx.x == 0) cnt_s = 0;
    __syncthreads();
    unsigned short u = xr[threadIdx.x & 255];
    int ex = (u >> 7) & 0xFF;
    int ok = (ex == 0) || (ex >= 100 && ex <= 140);
    if (threadIdx.x < 256) atomicAdd(&cnt_s, ok);
    __syncthreads();
    return (cnt_s >= 240) ? 1 : 0;   // 1 = bf16 inputs
}

// ---------------- pre: zero cnt+sums | detect->flag | swizzle lin_w | graph ranges ----------------
constexpr int NZ  = N + G * HC;            // ints to zero (cnt + sums)
constexpr int NZB = (NZ + 255) / 256;      // 452
__global__ __launch_bounds__(256) void k_pre(const unsigned short* __restrict__ xr,
                                             const void* __restrict__ w,
                                             const int* __restrict__ batch,
                                             int* __restrict__ flag,
                                             int* __restrict__ zp,
                                             unsigned short* __restrict__ bswz,
                                             int* __restrict__ gs) {
    int b = blockIdx.x;
    if (b < NZB) {
        int i = b * 256 + threadIdx.x;
        if (i < NZ) zp[i] = 0;
        if (b == 0) {
            int isbf = block_detect(xr);
            if (threadIdx.x == 0) *flag = isbf;
        }
    } else if (b < NZB + 40) {
        int isbf = block_detect(xr);
        int fb = (b - NZB) * 4 + (threadIdx.x >> 6);   // kb*16+nb, 0..159
        if (fb < 160) {
            int kb = fb >> 4, nb = fb & 15;
            int lane = threadIdx.x & 63;
            int q = lane >> 4, cl = lane & 15;
            int n = nb * 16 + cl;
            unsigned short v[8];
#pragma unroll
            for (int j = 0; j < 8; j++) {
                int k = kb * 32 + q * 8 + j;
                float f = (k < NIN) ? ldin(w, isbf, (size_t)k * HC + n) : 0.f;
                v[j] = f2us(f);
            }
            ushort4* dst = (ushort4*)(bswz + ((size_t)fb * 64 + lane) * 8);
            dst[0] = make_ushort4(v[0], v[1], v[2], v[3]);
            dst[1] = make_ushort4(v[4], v[5], v[6], v[7]);
        }
    } else {
        int g = threadIdx.x;   // graph start offsets, batch sorted
        int lo = 0, hi = N;
        while (lo < hi) {
            int mid = (lo + hi) >> 1;
            if (batch[mid] < g) lo = mid + 1;
            else hi = mid;
        }
        gs[g] = lo;
        if (g == 0) gs[G] = N;
    }
}

// ---------------- h = x @ lin_w via MFMA, direct x read, att dots fused ----------------
__global__ __launch_bounds__(256) void k_lin_mfma(const void* __restrict__ x,
                                                  const unsigned short* __restrict__ bswz,
                                                  const void* __restrict__ att_s,
                                                  const void* __restrict__ att_d,
                                                  unsigned short* __restrict__ hb,
                                                  float* __restrict__ a_src,
                                                  float* __restrict__ a_dst,
                                                  const int* __restrict__ flag) {
    int isbf = *flag;
    int wave = threadIdx.x >> 6, lane = threadIdx.x & 63;
    int q = lane >> 4, cl = lane & 15;
    int m0 = blockIdx.x * 64 + wave * 16;
    int row = m0 + cl; if (row >= N) row = N - 1;
    short8 a[NKB];
    if (isbf) {
        const unsigned short* xr = (const unsigned short*)x + (size_t)row * NIN + q * 8;
#pragma unroll
        for (int kb = 0; kb < 9; kb++) {
            ushort4 lo = *(const ushort4*)(xr + kb * 32);
            ushort4 hi = *(const ushort4*)(xr + kb * 32 + 4);
            a[kb] = pack8u(lo, hi);
        }
        ushort4 z = make_ushort4(0, 0, 0, 0);
        ushort4 lo = z, hi = z;
        if (q == 0)      { lo = *(const ushort4*)(xr + 288); hi = *(const ushort4*)(xr + 292); }
        else if (q == 1) { lo = *(const ushort4*)(xr + 288); }           // k=296..299
        a[9] = pack8u(lo, hi);
    } else {
        const float* xf = (const float*)x + (size_t)row * NIN + q * 8;
#pragma unroll
        for (int kb = 0; kb < 9; kb++) {
            float4 lo = *(const float4*)(xf + kb * 32);
            float4 hi = *(const float4*)(xf + kb * 32 + 4);
            a[kb] = pack8f(lo, hi);
        }
        float4 zf = make_float4(0.f, 0.f, 0.f, 0.f);
        float4 lo = zf, hi = zf;
        if (q == 0)      { lo = *(const float4*)(xf + 288); hi = *(const float4*)(xf + 292); }
        else if (q == 1) { lo = *(const float4*)(xf + 288); }
        a[9] = pack8f(lo, hi);
    }
    f32x4 acc[16];
#pragma unroll
    for (int nb = 0; nb < 16; nb++) acc[nb] = f32x4{0.f, 0.f, 0.f, 0.f};
#pragma unroll
    for (int kb = 0; kb < NKB; kb++) {
#pragma unroll
        for (int nb = 0; nb < 16; nb++) {
            short8 bfr = *(const short8*)(bswz + ((size_t)(kb * 16 + nb) * 64 + lane) * 8);
            acc[nb] = __builtin_amdgcn_mfma_f32_16x16x32_bf16(a[kb], bfr, acc[nb], 0, 0, 0);
        }
    }
    // epilogue: store h (bf16) + per-head attention partials
    float ps[4][4], pd[4][4];
#pragma unroll
    for (int hh = 0; hh < 4; hh++)
#pragma unroll
        for (int r = 0; r < 4; r++) { ps[hh][r] = 0.f; pd[hh][r] = 0.f; }
#pragma unroll
    for (int nb = 0; nb < 16; nb++) {
        float as_ = ldin(att_s, isbf, nb * 16 + cl);
        float ad_ = ldin(att_d, isbf, nb * 16 + cl);
        int hh = nb >> 2;
#pragma unroll
        for (int r = 0; r < 4; r++) {
            float v = acc[nb][r];
            ps[hh][r] += v * as_;
            pd[hh][r] += v * ad_;
            int gm = m0 + q * 4 + r;
            if (gm < N) hb[(size_t)gm * HC + nb * 16 + cl] = f2us(v);
        }
    }
#pragma unroll
    for (int hh = 0; hh < 4; hh++) {
#pragma unroll
        for (int r = 0; r < 4; r++) {
            float vs = ps[hh][r], vd = pd[hh][r];
#pragma unroll
            for (int m = 1; m < 16; m <<= 1) {
                vs += __shfl_xor(vs, m, 64);
                vd += __shfl_xor(vd, m, 64);
            }
            int gm = m0 + q * 4 + r;
            if (cl == 0 && gm < N) {
                a_src[gm * 4 + hh] = vs;
                a_dst[gm * 4 + hh] = vd;
            }
        }
    }
}

// ---------------- degree histogram ----------------
__global__ void k_hist(const int* __restrict__ dst, int* __restrict__ cnt) {
    int e = blockIdx.x * 256 + threadIdx.x;
    if (e < E) atomicAdd(&cnt[dst[e]], 1);
}

// ---------------- scan phase 1: per-block sums ----------------
__global__ __launch_bounds__(256) void k_scan1(const int* __restrict__ cnt, int* __restrict__ bsum) {
    __shared__ int wsum[4];
    int idx = blockIdx.x * 256 + threadIdx.x;
    int v = (idx < N) ? cnt[idx] : 0;
#pragma unroll
    for (int o2 = 32; o2; o2 >>= 1) v += __shfl_down(v, o2, 64);
    if ((threadIdx.x & 63) == 0) wsum[threadIdx.x >> 6] = v;
    __syncthreads();
    if (threadIdx.x == 0) bsum[blockIdx.x] = wsum[0] + wsum[1] + wsum[2] + wsum[3];
}

// ---------------- scan phases 2+3 merged: every block scans bsum, then its chunk ----------------
__global__ __launch_bounds__(256) void k_scan23(const int* __restrict__ bsum, int nb,
                                                const int* __restrict__ cnt,
                                                int* __restrict__ off, int* __restrict__ cur) {
    __shared__ int sd[256];
    __shared__ int s_boff;
    int t = threadIdx.x;
    int v = (t < nb) ? bsum[t] : 0;
    sd[t] = v;
    __syncthreads();
    for (int d = 1; d < 256; d <<= 1) {
        int u = (t >= d) ? sd[t - d] : 0;
        __syncthreads();
        sd[t] += u;
        __syncthreads();
    }
    if (t == (int)blockIdx.x) s_boff = sd[t] - v;     // exclusive prefix of this block
    if (blockIdx.x == 0 && t == nb - 1) off[N] = sd[t];
    __syncthreads();
    int boff = s_boff;
    int idx = blockIdx.x * 256 + t;
    int c = (idx < N) ? cnt[idx] : 0;
    __syncthreads();
    sd[t] = c;
    __syncthreads();
    for (int d = 1; d < 256; d <<= 1) {
        int u = (t >= d) ? sd[t - d] : 0;
        __syncthreads();
        sd[t] += u;
        __syncthreads();
    }
    int ex = sd[t] - c + boff;
    if (idx < N) { off[idx] = ex; cur[idx] = ex; }
}

// ---------------- scatter edges into CSR + per-edge softmax weights ----------------
__global__ void k_scatter(const int* __restrict__ ei,
                          const float* __restrict__ a_src,
                          const float* __restrict__ a_dst,
                          int* __restrict__ cur,
                          int* __restrict__ csr_s,
                          float* __restrict__ csr_w) {
    int e = blockIdx.x * 256 + threadIdx.x;
    if (e >= E) return;
    int s = ei[e], d = ei[E + e];
    float4 as = *(const float4*)&a_src[(size_t)s * 4];
    float4 ad = *(const float4*)&a_dst[(size_t)d * 4];
    float4 w;
    w.x = __expf(lrelu_att(as.x + ad.x));
    w.y = __expf(lrelu_att(as.y + ad.y));
    w.z = __expf(lrelu_att(as.z + ad.z));
    w.w = __expf(lrelu_att(as.w + ad.w));
    int pos = atomicAdd(&cur[d], 1);
    csr_s[pos] = s;
    *(float4*)&csr_w[(size_t)pos * 4] = w;
}

// ---------------- per-node aggregation: pure gather+FMA, weights precomputed ----------------
__global__ __launch_bounds__(256) void k_agg(const unsigned short* __restrict__ hb,
                                             const float* __restrict__ a_src,
                                             const float* __restrict__ a_dst,
                                             const int* __restrict__ off,
                                             const int* __restrict__ csr_s,
                                             const float* __restrict__ csr_w,
                                             const void* __restrict__ bias,
                                             unsigned short* __restrict__ outn,
                                             const int* __restrict__ flag) {
    int isbf = *flag;
    int wave = threadIdx.x >> 6, lane = threadIdx.x & 63;
    int n = blockIdx.x * 4 + wave;
    if (n >= N) return;
    int head = lane >> 4;
    float wself = __expf(lrelu_att(a_src[n * 4 + head] + a_dst[n * 4 + head]));
    ushort4 hv = *(const ushort4*)&hb[(size_t)n * HC + lane * 4];
    float4 acc;
    acc.x = us2f(hv.x) * wself;
    acc.y = us2f(hv.y) * wself;
    acc.z = us2f(hv.z) * wself;
    acc.w = us2f(hv.w) * wself;
    float ssum = wself;
    int p0 = off[n], p1 = off[n + 1];
    int i0 = 0, i1 = 0, i2 = 0, i3 = 0;
    if (p0 + 4 <= p1) { i0 = csr_s[p0]; i1 = csr_s[p0 + 1]; i2 = csr_s[p0 + 2]; i3 = csr_s[p0 + 3]; }
    int p = p0;
    for (; p + 4 <= p1; p += 4) {
        int s0 = i0, s1 = i1, s2 = i2, s3 = i3;
        ushort4 g0 = *(const ushort4*)&hb[(size_t)s0 * HC + lane * 4];
        ushort4 g1 = *(const ushort4*)&hb[(size_t)s1 * HC + lane * 4];
        ushort4 g2 = *(const ushort4*)&hb[(size_t)s2 * HC + lane * 4];
        ushort4 g3 = *(const ushort4*)&hb[(size_t)s3 * HC + lane * 4];
        float w0 = csr_w[(size_t)(p + 0) * 4 + head];
        float w1 = csr_w[(size_t)(p + 1) * 4 + head];
        float w2 = csr_w[(size_t)(p + 2) * 4 + head];
        float w3 = csr_w[(size_t)(p + 3) * 4 + head];
        int nn = p + 4;
        if (nn + 4 <= p1) { i0 = csr_s[nn]; i1 = csr_s[nn + 1]; i2 = csr_s[nn + 2]; i3 = csr_s[nn + 3]; }
        acc.x += us2f(g0.x) * w0 + us2f(g1.x) * w1 + us2f(g2.x) * w2 + us2f(g3.x) * w3;
        acc.y += us2f(g0.y) * w0 + us2f(g1.y) * w1 + us2f(g2.y) * w2 + us2f(g3.y) * w3;
        acc.z += us2f(g0.z) * w0 + us2f(g1.z) * w1 + us2f(g2.z) * w2 + us2f(g3.z) * w3;
        acc.w += us2f(g0.w) * w0 + us2f(g1.w) * w1 + us2f(g2.w) * w2 + us2f(g3.w) * w3;
        ssum += (w0 + w1) + (w2 + w3);
    }
    for (; p < p1; p++) {
        int s = csr_s[p];
        float wv = csr_w[(size_t)p * 4 + head];
        ushort4 hs = *(const ushort4*)&hb[(size_t)s * HC + lane * 4];
        acc.x += us2f(hs.x) * wv;
        acc.y += us2f(hs.y) * wv;
        acc.z += us2f(hs.z) * wv;
        acc.w += us2f(hs.w) * wv;
        ssum += wv;
    }
    float inv = 1.f / ssum;
    ushort4 o;
    o.x = f2us(lrelu_act(acc.x * inv + ldin(bias, isbf, lane * 4 + 0)));
    o.y = f2us(lrelu_act(acc.y * inv + ldin(bias, isbf, lane * 4 + 1)));
    o.z = f2us(lrelu_act(acc.z * inv + ldin(bias, isbf, lane * 4 + 2)));
    o.w = f2us(lrelu_act(acc.w * inv + ldin(bias, isbf, lane * 4 + 3)));
    *(ushort4*)&outn[(size_t)n * HC + lane * 4] = o;
}

// ---------------- pooling: (graph, quarter) grid ----------------
__global__ __launch_bounds__(256) void k_pool2(const unsigned short* __restrict__ outn,
                                               const int* __restrict__ gs,
                                               float* __restrict__ sums) {
    int g = blockIdx.x, qq = blockIdx.y, t = threadIdx.x;
    int s = gs[g], e2 = gs[g + 1];
    int len = e2 - s;
    int r0 = s + (len * qq) / 4;
    int r1 = s + (len * (qq + 1)) / 4;
    float a0 = 0.f, a1 = 0.f, a2 = 0.f, a3 = 0.f;
    int r = r0;
    for (; r + 4 <= r1; r += 4) {
        a0 += us2f(outn[(size_t)(r + 0) * HC + t]);
        a1 += us2f(outn[(size_t)(r + 1) * HC + t]);
        a2 += us2f(outn[(size_t)(r + 2) * HC + t]);
        a3 += us2f(outn[(size_t)(r + 3) * HC + t]);
    }
    for (; r < r1; r++) a0 += us2f(outn[(size_t)r * HC + t]);
    float v = (a0 + a1) + (a2 + a3);
    if (r1 > r0) atomicAdd(&sums[(size_t)g * HC + t], v);
}

// ---------------- final FC (mean-divide folded in, dual-dtype out) ----------------
__global__ __launch_bounds__(256) void k_fc(const float* __restrict__ sums,
                                            const int* __restrict__ gs,
                                            const void* __restrict__ fw,
                                            const void* __restrict__ fb,
                                            void* __restrict__ out,
                                            const int* __restrict__ flag) {
    __shared__ float pl[HC];
    int isbf = *flag;
    int g = blockIdx.y;
    int o = blockIdx.x * 256 + threadIdx.x;
    int c = gs[g + 1] - gs[g];
    float inv = 1.f / (float)(c > 1 ? c : 1);
    pl[threadIdx.x] = sums[(size_t)g * HC + threadIdx.x] * inv;
    __syncthreads();
    float acc = ldin(fb, isbf, o);
#pragma unroll 8
    for (int k = 0; k < HC; k++) acc += pl[k] * ldin(fw, isbf, (size_t)k * NOUT + o);
    size_t oi = (size_t)g * NOUT + o;
    if (isbf) ((bf16*)out)[oi] = __float2bfloat16(acc);
    else      ((float*)out)[oi] = acc;
}

extern "C" void kernel_launch(void* const* d_in, const int* in_sizes, int n_in,
                              void* d_out, int out_size, void* d_ws, size_t ws_size,
                              hipStream_t stream) {
    const void* x     = d_in[0];
    const int*  ei    = (const int*)d_in[1];
    const int*  batch = (const int*)d_in[2];
    const void* lin_w = d_in[3];
    const void* att_s = d_in[4];
    const void* att_d = d_in[5];
    const void* bias  = d_in[6];
    const void* fc1w  = d_in[7];
    const void* fc1b  = d_in[8];

    char* p = (char*)d_ws;
    unsigned short* hb   = (unsigned short*)p; p += (size_t)N * HC * 2;   // 25.6 MB
    unsigned short* outn = (unsigned short*)p; p += (size_t)N * HC * 2;   // 25.6 MB
    float* a_src  = (float*)p; p += (size_t)N * H * 4;
    float* a_dst  = (float*)p; p += (size_t)N * H * 4;
    int* cnt      = (int*)p;   p += (size_t)N * 4;                        // cnt+sums zeroed together
    float* sums   = (float*)p; p += (size_t)G * HC * 4;
    int* off      = (int*)p;   p += (size_t)(N + 4) * 4;
    int* cur      = (int*)p;   p += (size_t)N * 4;
    int* csr_s    = (int*)p;   p += (size_t)E * 4;                        // 3.2 MB
    float* csr_w  = (float*)p; p += (size_t)E * H * 4;                    // 12.8 MB
    unsigned short* bswz = (unsigned short*)p; p += (size_t)160 * 64 * 8 * 2;
    int* bsum     = (int*)p;   p += 1024;
    int* gs       = (int*)p;   p += (size_t)(G + 4) * 4;
    int* flag     = (int*)p;   p += 16;

    const int NB = (N + 255) / 256;  // 196

    k_pre<<<NZB + 40 + 1, 256, 0, stream>>>((const unsigned short*)x, lin_w, batch,
                                            flag, cnt, bswz, gs);
    k_lin_mfma<<<MP / 64, 256, 0, stream>>>(x, bswz, att_s, att_d, hb, a_src, a_dst, flag);
    k_hist<<<(E + 255) / 256, 256, 0, stream>>>(ei + E, cnt);
    k_scan1<<<NB, 256, 0, stream>>>(cnt, bsum);
    k_scan23<<<NB, 256, 0, stream>>>(bsum, NB, cnt, off, cur);
    k_scatter<<<(E + 255) / 256, 256, 0, stream>>>(ei, a_src, a_dst, cur, csr_s, csr_w);
    k_agg<<<(N + 3) / 4, 256, 0, stream>>>(hb, a_src, a_dst, off, csr_s, csr_w, bias, outn, flag);
    k_pool2<<<dim3(G, 4), 256, 0, stream>>>(outn, gs, sums);
    k_fc<<<dim3(NOUT / 256, G), 256, 0, stream>>>(sums, gs, fc1w, fc1b, d_out, flag);
}

// Round 6
// 366.484 us; speedup vs baseline: 1.0324x; 1.0324x over previous
//
#include <hip/hip_runtime.h>
#include <hip/hip_bf16.h>

using bf16 = __hip_bfloat16;
typedef __attribute__((ext_vector_type(8))) short short8;
typedef __attribute__((ext_vector_type(4))) float f32x4;

constexpr int N   = 50000;
constexpr int E   = 800000;
constexpr int NIN = 300;
constexpr int H   = 4;
constexpr int C   = 64;
constexpr int HC  = H * C;      // 256
constexpr int G   = 256;
constexpr int NOUT = 768;
constexpr int KP  = 320;        // K padded to 10*32
constexpr int NKB = 10;         // K blocks of 32
constexpr int MP  = 50048;      // M padded to 782*64

__device__ __forceinline__ float b2f(bf16 v) { return __bfloat162float(v); }
__device__ __forceinline__ float us2f(unsigned short u) {
    bf16 b; *(unsigned short*)&b = u; return __bfloat162float(b);
}
__device__ __forceinline__ unsigned short f2us(float f) {
    bf16 b = __float2bfloat16(f); return *(unsigned short*)&b;
}
__device__ __forceinline__ float lrelu_att(float v) { return v > 0.f ? v : 0.2f * v; }
__device__ __forceinline__ float lrelu_act(float v) { return v > 0.f ? v : 0.01f * v; }
__device__ __forceinline__ float ldin(const void* p, int isbf, size_t i) {
    return isbf ? b2f(((const bf16*)p)[i]) : ((const float*)p)[i];
}

// in-block dtype detection (reads first 256 uint16s of x; deterministic)
__device__ __forceinline__ int block_detect(const unsigned short* __restrict__ xr) {
    __shared__ int cnt_s;
    if (threadIdx.x == 0) cnt_s = 0;
    __syncthreads();
    unsigned short u = xr[threadIdx.x & 255];
    int ex = (u >> 7) & 0xFF;
    int ok = (ex == 0) || (ex >= 100 && ex <= 140);
    if (threadIdx.x < 256) atomicAdd(&cnt_s, ok);
    __syncthreads();
    return (cnt_s >= 240) ? 1 : 0;   // 1 = bf16 inputs
}

// ---------------- pre: zero | detect | swizzle w | ranges | x->xb staging ----------------
constexpr int NZ   = N + G * HC;            // ints to zero (cnt + sums)
constexpr int NZB  = (NZ + 255) / 256;      // 452
constexpr int NCVT = MP * KP / 4 / 256;     // 15640 (exact)
__global__ __launch_bounds__(256) void k_pre(const unsigned short* __restrict__ xr,
                                             const void* __restrict__ x,
                                             const void* __restrict__ w,
                                             const int* __restrict__ batch,
                                             int* __restrict__ flag,
                                             int* __restrict__ zp,
                                             unsigned short* __restrict__ bswz,
                                             unsigned short* __restrict__ xb,
                                             int* __restrict__ gs) {
    int b = blockIdx.x;
    if (b < NZB) {
        int i = b * 256 + threadIdx.x;
        if (i < NZ) zp[i] = 0;
        if (b == 0) {
            int isbf = block_detect(xr);
            if (threadIdx.x == 0) *flag = isbf;
        }
    } else if (b < NZB + 40) {
        int isbf = block_detect(xr);
        int fb = (b - NZB) * 4 + (threadIdx.x >> 6);   // kb*16+nb, 0..159
        if (fb < 160) {
            int kb = fb >> 4, nb = fb & 15;
            int lane = threadIdx.x & 63;
            int q = lane >> 4, cl = lane & 15;
            int n = nb * 16 + cl;
            unsigned short v[8];
#pragma unroll
            for (int j = 0; j < 8; j++) {
                int k = kb * 32 + q * 8 + j;
                float f = (k < NIN) ? ldin(w, isbf, (size_t)k * HC + n) : 0.f;
                v[j] = f2us(f);
            }
            ushort4* dst = (ushort4*)(bswz + ((size_t)fb * 64 + lane) * 8);
            dst[0] = make_ushort4(v[0], v[1], v[2], v[3]);
            dst[1] = make_ushort4(v[4], v[5], v[6], v[7]);
        }
    } else if (b == NZB + 40) {
        int g = threadIdx.x;   // graph start offsets, batch sorted
        int lo = 0, hi = N;
        while (lo < hi) {
            int mid = (lo + hi) >> 1;
            if (batch[mid] < g) lo = mid + 1;
            else hi = mid;
        }
        gs[g] = lo;
        if (g == 0) gs[G] = N;
    } else {
        int isbf = block_detect(xr);      // uniform participation before any divergence
        unsigned int tid = (b - (NZB + 41)) * 256 + threadIdx.x;
        unsigned int idx = tid * 4;       // element index in xb (row*KP+col)
        int row = idx / KP;
        int col = idx - row * KP;
        ushort4 o;
        if (row >= N || col >= NIN) {     // NIN%4==0: 4-group all-in or all-out
            o = make_ushort4(0, 0, 0, 0);
        } else {
            size_t src = (size_t)row * NIN + col;
            if (isbf) {
                o = *(const ushort4*)((const unsigned short*)x + src);
            } else {
                float4 f = *(const float4*)((const float*)x + src);
                o = make_ushort4(f2us(f.x), f2us(f.y), f2us(f.z), f2us(f.w));
            }
        }
        *(ushort4*)(xb + idx) = o;
    }
}

// ---------------- h = x @ lin_w via MFMA; batched B-loads; att dots fused ----------------
__global__ __launch_bounds__(256) void k_lin_mfma(const unsigned short* __restrict__ xb,
                                                  const unsigned short* __restrict__ bswz,
                                                  const void* __restrict__ att_s,
                                                  const void* __restrict__ att_d,
                                                  unsigned short* __restrict__ hb,
                                                  float* __restrict__ a_src,
                                                  float* __restrict__ a_dst,
                                                  const int* __restrict__ flag) {
    int isbf = *flag;
    int wave = threadIdx.x >> 6, lane = threadIdx.x & 63;
    int q = lane >> 4, cl = lane & 15;
    int m0 = blockIdx.x * 64 + wave * 16;
    const unsigned short* arow = xb + (size_t)(m0 + cl) * KP + q * 8;
    short8 a[NKB];
#pragma unroll
    for (int kb = 0; kb < NKB; kb++) a[kb] = *(const short8*)(arow + kb * 32);
    f32x4 acc[16];
#pragma unroll
    for (int nb = 0; nb < 16; nb++) acc[nb] = f32x4{0.f, 0.f, 0.f, 0.f};
#pragma unroll
    for (int kb = 0; kb < NKB; kb++) {
        short8 bfr[16];                    // 16 independent loads in flight per kb round
#pragma unroll
        for (int nb = 0; nb < 16; nb++)
            bfr[nb] = *(const short8*)(bswz + ((size_t)(kb * 16 + nb) * 64 + lane) * 8);
#pragma unroll
        for (int nb = 0; nb < 16; nb++)
            acc[nb] = __builtin_amdgcn_mfma_f32_16x16x32_bf16(a[kb], bfr[nb], acc[nb], 0, 0, 0);
    }
    // epilogue: store h (bf16) + per-head attention partials
    float ps[4][4], pd[4][4];
#pragma unroll
    for (int hh = 0; hh < 4; hh++)
#pragma unroll
        for (int r = 0; r < 4; r++) { ps[hh][r] = 0.f; pd[hh][r] = 0.f; }
#pragma unroll
    for (int nb = 0; nb < 16; nb++) {
        float as_ = ldin(att_s, isbf, nb * 16 + cl);
        float ad_ = ldin(att_d, isbf, nb * 16 + cl);
        int hh = nb >> 2;
#pragma unroll
        for (int r = 0; r < 4; r++) {
            float v = acc[nb][r];
            ps[hh][r] += v * as_;
            pd[hh][r] += v * ad_;
            int gm = m0 + q * 4 + r;
            if (gm < N) hb[(size_t)gm * HC + nb * 16 + cl] = f2us(v);
        }
    }
#pragma unroll
    for (int hh = 0; hh < 4; hh++) {
#pragma unroll
        for (int r = 0; r < 4; r++) {
            float vs = ps[hh][r], vd = pd[hh][r];
#pragma unroll
            for (int m = 1; m < 16; m <<= 1) {
                vs += __shfl_xor(vs, m, 64);
                vd += __shfl_xor(vd, m, 64);
            }
            int gm = m0 + q * 4 + r;
            if (cl == 0 && gm < N) {
                a_src[gm * 4 + hh] = vs;
                a_dst[gm * 4 + hh] = vd;
            }
        }
    }
}

// ---------------- degree histogram ----------------
__global__ void k_hist(const int* __restrict__ dst, int* __restrict__ cnt) {
    int e = blockIdx.x * 256 + threadIdx.x;
    if (e < E) atomicAdd(&cnt[dst[e]], 1);
}

// ---------------- scan phase 1: per-block sums ----------------
__global__ __launch_bounds__(256) void k_scan1(const int* __restrict__ cnt, int* __restrict__ bsum) {
    __shared__ int wsum[4];
    int idx = blockIdx.x * 256 + threadIdx.x;
    int v = (idx < N) ? cnt[idx] : 0;
#pragma unroll
    for (int o2 = 32; o2; o2 >>= 1) v += __shfl_down(v, o2, 64);
    if ((threadIdx.x & 63) == 0) wsum[threadIdx.x >> 6] = v;
    __syncthreads();
    if (threadIdx.x == 0) bsum[blockIdx.x] = wsum[0] + wsum[1] + wsum[2] + wsum[3];
}

// ---------------- scan phases 2+3 merged ----------------
__global__ __launch_bounds__(256) void k_scan23(const int* __restrict__ bsum, int nb,
                                                const int* __restrict__ cnt,
                                                int* __restrict__ off, int* __restrict__ cur) {
    __shared__ int sd[256];
    __shared__ int s_boff;
    int t = threadIdx.x;
    int v = (t < nb) ? bsum[t] : 0;
    sd[t] = v;
    __syncthreads();
    for (int d = 1; d < 256; d <<= 1) {
        int u = (t >= d) ? sd[t - d] : 0;
        __syncthreads();
        sd[t] += u;
        __syncthreads();
    }
    if (t == (int)blockIdx.x) s_boff = sd[t] - v;
    if (blockIdx.x == 0 && t == nb - 1) off[N] = sd[t];
    __syncthreads();
    int boff = s_boff;
    int idx = blockIdx.x * 256 + t;
    int c = (idx < N) ? cnt[idx] : 0;
    __syncthreads();
    sd[t] = c;
    __syncthreads();
    for (int d = 1; d < 256; d <<= 1) {
        int u = (t >= d) ? sd[t - d] : 0;
        __syncthreads();
        sd[t] += u;
        __syncthreads();
    }
    int ex = sd[t] - c + boff;
    if (idx < N) { off[idx] = ex; cur[idx] = ex; }
}

// ---------------- scatter edges into CSR + per-edge softmax weights ----------------
__global__ void k_scatter(const int* __restrict__ ei,
                          const float* __restrict__ a_src,
                          const float* __restrict__ a_dst,
                          int* __restrict__ cur,
                          int* __restrict__ csr_s,
                          float* __restrict__ csr_w) {
    int e = blockIdx.x * 256 + threadIdx.x;
    if (e >= E) return;
    int s = ei[e], d = ei[E + e];
    float4 as = *(const float4*)&a_src[(size_t)s * 4];
    float4 ad = *(const float4*)&a_dst[(size_t)d * 4];
    float4 w;
    w.x = __expf(lrelu_att(as.x + ad.x));
    w.y = __expf(lrelu_att(as.y + ad.y));
    w.z = __expf(lrelu_att(as.z + ad.z));
    w.w = __expf(lrelu_att(as.w + ad.w));
    int pos = atomicAdd(&cur[d], 1);
    csr_s[pos] = s;
    *(float4*)&csr_w[(size_t)pos * 4] = w;
}

// ---------------- per-node aggregation: pure gather+FMA ----------------
__global__ __launch_bounds__(256) void k_agg(const unsigned short* __restrict__ hb,
                                             const float* __restrict__ a_src,
                                             const float* __restrict__ a_dst,
                                             const int* __restrict__ off,
                                             const int* __restrict__ csr_s,
                                             const float* __restrict__ csr_w,
                                             const void* __restrict__ bias,
                                             unsigned short* __restrict__ outn,
                                             const int* __restrict__ flag) {
    int isbf = *flag;
    int wave = threadIdx.x >> 6, lane = threadIdx.x & 63;
    int n = blockIdx.x * 4 + wave;
    if (n >= N) return;
    int head = lane >> 4;
    float wself = __expf(lrelu_att(a_src[n * 4 + head] + a_dst[n * 4 + head]));
    ushort4 hv = *(const ushort4*)&hb[(size_t)n * HC + lane * 4];
    float4 acc;
    acc.x = us2f(hv.x) * wself;
    acc.y = us2f(hv.y) * wself;
    acc.z = us2f(hv.z) * wself;
    acc.w = us2f(hv.w) * wself;
    float ssum = wself;
    int p0 = off[n], p1 = off[n + 1];
    int i0 = 0, i1 = 0, i2 = 0, i3 = 0;
    if (p0 + 4 <= p1) { i0 = csr_s[p0]; i1 = csr_s[p0 + 1]; i2 = csr_s[p0 + 2]; i3 = csr_s[p0 + 3]; }
    int p = p0;
    for (; p + 4 <= p1; p += 4) {
        int s0 = i0, s1 = i1, s2 = i2, s3 = i3;
        ushort4 g0 = *(const ushort4*)&hb[(size_t)s0 * HC + lane * 4];
        ushort4 g1 = *(const ushort4*)&hb[(size_t)s1 * HC + lane * 4];
        ushort4 g2 = *(const ushort4*)&hb[(size_t)s2 * HC + lane * 4];
        ushort4 g3 = *(const ushort4*)&hb[(size_t)s3 * HC + lane * 4];
        float w0 = csr_w[(size_t)(p + 0) * 4 + head];
        float w1 = csr_w[(size_t)(p + 1) * 4 + head];
        float w2 = csr_w[(size_t)(p + 2) * 4 + head];
        float w3 = csr_w[(size_t)(p + 3) * 4 + head];
        int nn = p + 4;
        if (nn + 4 <= p1) { i0 = csr_s[nn]; i1 = csr_s[nn + 1]; i2 = csr_s[nn + 2]; i3 = csr_s[nn + 3]; }
        acc.x += us2f(g0.x) * w0 + us2f(g1.x) * w1 + us2f(g2.x) * w2 + us2f(g3.x) * w3;
        acc.y += us2f(g0.y) * w0 + us2f(g1.y) * w1 + us2f(g2.y) * w2 + us2f(g3.y) * w3;
        acc.z += us2f(g0.z) * w0 + us2f(g1.z) * w1 + us2f(g2.z) * w2 + us2f(g3.z) * w3;
        acc.w += us2f(g0.w) * w0 + us2f(g1.w) * w1 + us2f(g2.w) * w2 + us2f(g3.w) * w3;
        ssum += (w0 + w1) + (w2 + w3);
    }
    for (; p < p1; p++) {
        int s = csr_s[p];
        float wv = csr_w[(size_t)p * 4 + head];
        ushort4 hs = *(const ushort4*)&hb[(size_t)s * HC + lane * 4];
        acc.x += us2f(hs.x) * wv;
        acc.y += us2f(hs.y) * wv;
        acc.z += us2f(hs.z) * wv;
        acc.w += us2f(hs.w) * wv;
        ssum += wv;
    }
    float inv = 1.f / ssum;
    ushort4 o;
    o.x = f2us(lrelu_act(acc.x * inv + ldin(bias, isbf, lane * 4 + 0)));
    o.y = f2us(lrelu_act(acc.y * inv + ldin(bias, isbf, lane * 4 + 1)));
    o.z = f2us(lrelu_act(acc.z * inv + ldin(bias, isbf, lane * 4 + 2)));
    o.w = f2us(lrelu_act(acc.w * inv + ldin(bias, isbf, lane * 4 + 3)));
    *(ushort4*)&outn[(size_t)n * HC + lane * 4] = o;
}

// ---------------- pooling: (graph, quarter) grid ----------------
__global__ __launch_bounds__(256) void k_pool2(const unsigned short* __restrict__ outn,
                                               const int* __restrict__ gs,
                                               float* __restrict__ sums) {
    int g = blockIdx.x, qq = blockIdx.y, t = threadIdx.x;
    int s = gs[g], e2 = gs[g + 1];
    int len = e2 - s;
    int r0 = s + (len * qq) / 4;
    int r1 = s + (len * (qq + 1)) / 4;
    float a0 = 0.f, a1 = 0.f, a2 = 0.f, a3 = 0.f;
    int r = r0;
    for (; r + 4 <= r1; r += 4) {
        a0 += us2f(outn[(size_t)(r + 0) * HC + t]);
        a1 += us2f(outn[(size_t)(r + 1) * HC + t]);
        a2 += us2f(outn[(size_t)(r + 2) * HC + t]);
        a3 += us2f(outn[(size_t)(r + 3) * HC + t]);
    }
    for (; r < r1; r++) a0 += us2f(outn[(size_t)r * HC + t]);
    float v = (a0 + a1) + (a2 + a3);
    if (r1 > r0) atomicAdd(&sums[(size_t)g * HC + t], v);
}

// ---------------- final FC (mean-divide folded in, dual-dtype out) ----------------
__global__ __launch_bounds__(256) void k_fc(const float* __restrict__ sums,
                                            const int* __restrict__ gs,
                                            const void* __restrict__ fw,
                                            const void* __restrict__ fb,
                                            void* __restrict__ out,
                                            const int* __restrict__ flag) {
    __shared__ float pl[HC];
    int isbf = *flag;
    int g = blockIdx.y;
    int o = blockIdx.x * 256 + threadIdx.x;
    int c = gs[g + 1] - gs[g];
    float inv = 1.f / (float)(c > 1 ? c : 1);
    pl[threadIdx.x] = sums[(size_t)g * HC + threadIdx.x] * inv;
    __syncthreads();
    float acc = ldin(fb, isbf, o);
#pragma unroll 8
    for (int k = 0; k < HC; k++) acc += pl[k] * ldin(fw, isbf, (size_t)k * NOUT + o);
    size_t oi = (size_t)g * NOUT + o;
    if (isbf) ((bf16*)out)[oi] = __float2bfloat16(acc);
    else      ((float*)out)[oi] = acc;
}

extern "C" void kernel_launch(void* const* d_in, const int* in_sizes, int n_in,
                              void* d_out, int out_size, void* d_ws, size_t ws_size,
                              hipStream_t stream) {
    const void* x     = d_in[0];
    const int*  ei    = (const int*)d_in[1];
    const int*  batch = (const int*)d_in[2];
    const void* lin_w = d_in[3];
    const void* att_s = d_in[4];
    const void* att_d = d_in[5];
    const void* bias  = d_in[6];
    const void* fc1w  = d_in[7];
    const void* fc1b  = d_in[8];

    char* p = (char*)d_ws;
    unsigned short* xb = (unsigned short*)p; p += (size_t)MP * KP * 2;   // 32.0 MB (outn aliases)
    unsigned short* hb = (unsigned short*)p; p += (size_t)N * HC * 2;    // 25.6 MB
    float* a_src  = (float*)p; p += (size_t)N * H * 4;
    float* a_dst  = (float*)p; p += (size_t)N * H * 4;
    int* cnt      = (int*)p;   p += (size_t)N * 4;                       // cnt+sums zeroed together
    float* sums   = (float*)p; p += (size_t)G * HC * 4;
    int* off      = (int*)p;   p += (size_t)(N + 4) * 4;
    int* cur      = (int*)p;   p += (size_t)N * 4;
    int* csr_s    = (int*)p;   p += (size_t)E * 4;                       // 3.2 MB
    float* csr_w  = (float*)p; p += (size_t)E * H * 4;                   // 12.8 MB
    unsigned short* bswz = (unsigned short*)p; p += (size_t)160 * 64 * 8 * 2;
    int* bsum     = (int*)p;   p += 1024;
    int* gs       = (int*)p;   p += (size_t)(G + 4) * 4;
    int* flag     = (int*)p;   p += 16;
    unsigned short* outn = xb;   // alias: xb dead after k_lin_mfma, outn born at k_agg

    const int NB = (N + 255) / 256;  // 196

    k_pre<<<NZB + 41 + NCVT, 256, 0, stream>>>((const unsigned short*)x, x, lin_w, batch,
                                               flag, cnt, bswz, xb, gs);
    k_lin_mfma<<<MP / 64, 256, 0, stream>>>(xb, bswz, att_s, att_d, hb, a_src, a_dst, flag);
    k_hist<<<(E + 255) / 256, 256, 0, stream>>>(ei + E, cnt);
    k_scan1<<<NB, 256, 0, stream>>>(cnt, bsum);
    k_scan23<<<NB, 256, 0, stream>>>(bsum, NB, cnt, off, cur);
    k_scatter<<<(E + 255) / 256, 256, 0, stream>>>(ei, a_src, a_dst, cur, csr_s, csr_w);
    k_agg<<<(N + 3) / 4, 256, 0, stream>>>(hb, a_src, a_dst, off, csr_s, csr_w, bias, outn, flag);
    k_pool2<<<dim3(G, 4), 256, 0, stream>>>(outn, gs, sums);
    k_fc<<<dim3(NOUT / 256, G), 256, 0, stream>>>(sums, gs, fc1w, fc1b, d_out, flag);
}

// Round 7
// 357.659 us; speedup vs baseline: 1.0579x; 1.0247x over previous
//
#include <hip/hip_runtime.h>
#include <hip/hip_bf16.h>

using bf16 = __hip_bfloat16;
typedef __attribute__((ext_vector_type(8))) short short8;
typedef __attribute__((ext_vector_type(4))) float f32x4;

constexpr int N   = 50000;
constexpr int E   = 800000;
constexpr int NIN = 300;
constexpr int H   = 4;
constexpr int C   = 64;
constexpr int HC  = H * C;      // 256
constexpr int G   = 256;
constexpr int NOUT = 768;
constexpr int NKB = 10;         // K blocks of 32 (K padded 300->320)
constexpr int MP  = 50048;      // M padded to 782*64
constexpr int XSP = 328;        // LDS row pitch (bf16 elems): 16B-aligned, 2-way-bank-free

__device__ __forceinline__ float b2f(bf16 v) { return __bfloat162float(v); }
__device__ __forceinline__ float us2f(unsigned short u) {
    bf16 b; *(unsigned short*)&b = u; return __bfloat162float(b);
}
__device__ __forceinline__ unsigned short f2us(float f) {
    bf16 b = __float2bfloat16(f); return *(unsigned short*)&b;
}
__device__ __forceinline__ float lrelu_att(float v) { return v > 0.f ? v : 0.2f * v; }
__device__ __forceinline__ float lrelu_act(float v) { return v > 0.f ? v : 0.01f * v; }
__device__ __forceinline__ float ldin(const void* p, int isbf, size_t i) {
    return isbf ? b2f(((const bf16*)p)[i]) : ((const float*)p)[i];
}
// extract head's bf16 weight from packed edge record {s, w01, w23, pad}
__device__ __forceinline__ float wext(int4 e, int head) {
    int d = (head < 2) ? e.y : e.z;
    unsigned bits = (head & 1) ? (unsigned)(d & 0xFFFF0000u) : ((unsigned)d << 16);
    return __uint_as_float(bits);
}

// in-block dtype detection (reads first 256 uint16s of x; deterministic)
__device__ __forceinline__ int block_detect(const unsigned short* __restrict__ xr) {
    __shared__ int cnt_s;
    if (threadIdx.x == 0) cnt_s = 0;
    __syncthreads();
    unsigned short u = xr[threadIdx.x & 255];
    int ex = (u >> 7) & 0xFF;
    int ok = (ex == 0) || (ex >= 100 && ex <= 140);
    if (threadIdx.x < 256) atomicAdd(&cnt_s, ok);
    __syncthreads();
    return (cnt_s >= 240) ? 1 : 0;   // 1 = bf16 inputs
}

// ---------------- pre: zero | detect | swizzle w | graph ranges ----------------
constexpr int NZ  = N + G * HC;            // ints to zero (cnt + sums)
constexpr int NZB = (NZ + 255) / 256;      // 452
__global__ __launch_bounds__(256) void k_pre(const unsigned short* __restrict__ xr,
                                             const void* __restrict__ w,
                                             const int* __restrict__ batch,
                                             int* __restrict__ flag,
                                             int* __restrict__ zp,
                                             unsigned short* __restrict__ bswz,
                                             int* __restrict__ gs) {
    int b = blockIdx.x;
    if (b < NZB) {
        int i = b * 256 + threadIdx.x;
        if (i < NZ) zp[i] = 0;
        if (b == 0) {
            int isbf = block_detect(xr);
            if (threadIdx.x == 0) *flag = isbf;
        }
    } else if (b < NZB + 40) {
        int isbf = block_detect(xr);
        int fb = (b - NZB) * 4 + (threadIdx.x >> 6);   // kb*16+nb, 0..159
        if (fb < 160) {
            int kb = fb >> 4, nb = fb & 15;
            int lane = threadIdx.x & 63;
            int q = lane >> 4, cl = lane & 15;
            int n = nb * 16 + cl;
            unsigned short v[8];
#pragma unroll
            for (int j = 0; j < 8; j++) {
                int k = kb * 32 + q * 8 + j;
                float f = (k < NIN) ? ldin(w, isbf, (size_t)k * HC + n) : 0.f;
                v[j] = f2us(f);
            }
            ushort4* dst = (ushort4*)(bswz + ((size_t)fb * 64 + lane) * 8);
            dst[0] = make_ushort4(v[0], v[1], v[2], v[3]);
            dst[1] = make_ushort4(v[4], v[5], v[6], v[7]);
        }
    } else {
        int g = threadIdx.x;   // graph start offsets, batch sorted
        int lo = 0, hi = N;
        while (lo < hi) {
            int mid = (lo + hi) >> 1;
            if (batch[mid] < g) lo = mid + 1;
            else hi = mid;
        }
        gs[g] = lo;
        if (g == 0) gs[G] = N;
    }
}

// ---------------- h = x @ lin_w via MFMA; x staged through LDS; att dots fused ----------------
__global__ __launch_bounds__(256) void k_lin_mfma(const void* __restrict__ x,
                                                  const unsigned short* __restrict__ bswz,
                                                  const void* __restrict__ att_s,
                                                  const void* __restrict__ att_d,
                                                  unsigned short* __restrict__ hb,
                                                  float* __restrict__ a_src,
                                                  float* __restrict__ a_dst,
                                                  const int* __restrict__ flag) {
    __shared__ unsigned short xs[64][XSP];   // 41 KB
    int isbf = *flag;
    int t = threadIdx.x;
    int m0blk = blockIdx.x * 64;
    // ---- stage 64 rows of x into LDS (coalesced, dual-dtype) ----
    if (isbf) {
        const unsigned short* xp = (const unsigned short*)x;
        for (int gidx = t; gidx < 64 * 75; gidx += 256) {
            int r = gidx / 75, c = (gidx - r * 75) * 4;
            int row = m0blk + r; if (row >= N) row = N - 1;
            ushort4 v = *(const ushort4*)(xp + (size_t)row * NIN + c);
            *(ushort4*)&xs[r][c] = v;
        }
    } else {
        const float* xp = (const float*)x;
        for (int gidx = t; gidx < 64 * 75; gidx += 256) {
            int r = gidx / 75, c = (gidx - r * 75) * 4;
            int row = m0blk + r; if (row >= N) row = N - 1;
            float4 f = *(const float4*)(xp + (size_t)row * NIN + c);
            *(ushort4*)&xs[r][c] = make_ushort4(f2us(f.x), f2us(f.y), f2us(f.z), f2us(f.w));
        }
    }
    for (int i = t; i < 64 * 28; i += 256) {      // zero K-pad cols 300..327
        int r = i / 28, c = 300 + (i - r * 28);
        xs[r][c] = 0;
    }
    __syncthreads();

    int wave = t >> 6, lane = t & 63;
    int q = lane >> 4, cl = lane & 15;
    int m0 = m0blk + wave * 16;
    const unsigned short* abase = &xs[wave * 16 + cl][q * 8];
    short8 a[NKB];
#pragma unroll
    for (int kb = 0; kb < NKB; kb++) a[kb] = *(const short8*)(abase + kb * 32);
    f32x4 acc[16];
#pragma unroll
    for (int nb = 0; nb < 16; nb++) acc[nb] = f32x4{0.f, 0.f, 0.f, 0.f};
#pragma unroll
    for (int kb = 0; kb < NKB; kb++) {
        short8 bfr[16];                    // 16 independent loads in flight per kb round
#pragma unroll
        for (int nb = 0; nb < 16; nb++)
            bfr[nb] = *(const short8*)(bswz + ((size_t)(kb * 16 + nb) * 64 + lane) * 8);
#pragma unroll
        for (int nb = 0; nb < 16; nb++)
            acc[nb] = __builtin_amdgcn_mfma_f32_16x16x32_bf16(a[kb], bfr[nb], acc[nb], 0, 0, 0);
    }
    // epilogue: store h (bf16) + per-head attention partials
    float ps[4][4], pd[4][4];
#pragma unroll
    for (int hh = 0; hh < 4; hh++)
#pragma unroll
        for (int r = 0; r < 4; r++) { ps[hh][r] = 0.f; pd[hh][r] = 0.f; }
#pragma unroll
    for (int nb = 0; nb < 16; nb++) {
        float as_ = ldin(att_s, isbf, nb * 16 + cl);
        float ad_ = ldin(att_d, isbf, nb * 16 + cl);
        int hh = nb >> 2;
#pragma unroll
        for (int r = 0; r < 4; r++) {
            float v = acc[nb][r];
            ps[hh][r] += v * as_;
            pd[hh][r] += v * ad_;
            int gm = m0 + q * 4 + r;
            if (gm < N) hb[(size_t)gm * HC + nb * 16 + cl] = f2us(v);
        }
    }
#pragma unroll
    for (int hh = 0; hh < 4; hh++) {
#pragma unroll
        for (int r = 0; r < 4; r++) {
            float vs = ps[hh][r], vd = pd[hh][r];
#pragma unroll
            for (int m = 1; m < 16; m <<= 1) {
                vs += __shfl_xor(vs, m, 64);
                vd += __shfl_xor(vd, m, 64);
            }
            int gm = m0 + q * 4 + r;
            if (cl == 0 && gm < N) {
                a_src[gm * 4 + hh] = vs;
                a_dst[gm * 4 + hh] = vd;
            }
        }
    }
}

// ---------------- degree histogram ----------------
__global__ void k_hist(const int* __restrict__ dst, int* __restrict__ cnt) {
    int e = blockIdx.x * 256 + threadIdx.x;
    if (e < E) atomicAdd(&cnt[dst[e]], 1);
}

// ---------------- scan phase 1: per-block sums ----------------
__global__ __launch_bounds__(256) void k_scan1(const int* __restrict__ cnt, int* __restrict__ bsum) {
    __shared__ int wsum[4];
    int idx = blockIdx.x * 256 + threadIdx.x;
    int v = (idx < N) ? cnt[idx] : 0;
#pragma unroll
    for (int o2 = 32; o2; o2 >>= 1) v += __shfl_down(v, o2, 64);
    if ((threadIdx.x & 63) == 0) wsum[threadIdx.x >> 6] = v;
    __syncthreads();
    if (threadIdx.x == 0) bsum[blockIdx.x] = wsum[0] + wsum[1] + wsum[2] + wsum[3];
}

// ---------------- scan phases 2+3 merged ----------------
__global__ __launch_bounds__(256) void k_scan23(const int* __restrict__ bsum, int nb,
                                                const int* __restrict__ cnt,
                                                int* __restrict__ off, int* __restrict__ cur) {
    __shared__ int sd[256];
    __shared__ int s_boff;
    int t = threadIdx.x;
    int v = (t < nb) ? bsum[t] : 0;
    sd[t] = v;
    __syncthreads();
    for (int d = 1; d < 256; d <<= 1) {
        int u = (t >= d) ? sd[t - d] : 0;
        __syncthreads();
        sd[t] += u;
        __syncthreads();
    }
    if (t == (int)blockIdx.x) s_boff = sd[t] - v;
    if (blockIdx.x == 0 && t == nb - 1) off[N] = sd[t];
    __syncthreads();
    int boff = s_boff;
    int idx = blockIdx.x * 256 + t;
    int c = (idx < N) ? cnt[idx] : 0;
    __syncthreads();
    sd[t] = c;
    __syncthreads();
    for (int d = 1; d < 256; d <<= 1) {
        int u = (t >= d) ? sd[t - d] : 0;
        __syncthreads();
        sd[t] += u;
        __syncthreads();
    }
    int ex = sd[t] - c + boff;
    if (idx < N) { off[idx] = ex; cur[idx] = ex; }
}

// ---------------- scatter: packed 16B edge records {src, w0..3 bf16} ----------------
__global__ void k_scatter(const int* __restrict__ ei,
                          const float* __restrict__ a_src,
                          const float* __restrict__ a_dst,
                          int* __restrict__ cur,
                          int4* __restrict__ epack) {
    int e = blockIdx.x * 256 + threadIdx.x;
    if (e >= E) return;
    int s = ei[e], d = ei[E + e];
    float4 as = *(const float4*)&a_src[(size_t)s * 4];
    float4 ad = *(const float4*)&a_dst[(size_t)d * 4];
    unsigned w0 = f2us(__expf(lrelu_att(as.x + ad.x)));
    unsigned w1 = f2us(__expf(lrelu_att(as.y + ad.y)));
    unsigned w2 = f2us(__expf(lrelu_att(as.z + ad.z)));
    unsigned w3 = f2us(__expf(lrelu_att(as.w + ad.w)));
    int pos = atomicAdd(&cur[d], 1);
    int4 v;
    v.x = s;
    v.y = (int)(w0 | (w1 << 16));
    v.z = (int)(w2 | (w3 << 16));
    v.w = 0;
    epack[pos] = v;
}

// ---------------- per-node aggregation: unroll-8, packed records ----------------
__global__ __launch_bounds__(256) void k_agg(const unsigned short* __restrict__ hb,
                                             const float* __restrict__ a_src,
                                             const float* __restrict__ a_dst,
                                             const int* __restrict__ off,
                                             const int4* __restrict__ epack,
                                             const void* __restrict__ bias,
                                             unsigned short* __restrict__ outn,
                                             const int* __restrict__ flag) {
    int isbf = *flag;
    int wave = threadIdx.x >> 6, lane = threadIdx.x & 63;
    int n = blockIdx.x * 4 + wave;
    if (n >= N) return;
    int head = lane >> 4;
    float wself = __expf(lrelu_att(a_src[n * 4 + head] + a_dst[n * 4 + head]));
    ushort4 hv = *(const ushort4*)&hb[(size_t)n * HC + lane * 4];
    float4 acc;
    acc.x = us2f(hv.x) * wself;
    acc.y = us2f(hv.y) * wself;
    acc.z = us2f(hv.z) * wself;
    acc.w = us2f(hv.w) * wself;
    float ssum = wself;
    int p0 = off[n], p1 = off[n + 1];
    int4 er[8];
    if (p0 + 8 <= p1) {
#pragma unroll
        for (int j = 0; j < 8; j++) er[j] = epack[p0 + j];
    }
    int p = p0;
    for (; p + 8 <= p1; p += 8) {
        int ss[8]; float ww[8];
#pragma unroll
        for (int j = 0; j < 8; j++) { ss[j] = er[j].x; ww[j] = wext(er[j], head); }
        ushort4 gg[8];
#pragma unroll
        for (int j = 0; j < 8; j++) gg[j] = *(const ushort4*)&hb[(size_t)ss[j] * HC + lane * 4];
        int np = p + 8;
        if (np + 8 <= p1) {
#pragma unroll
            for (int j = 0; j < 8; j++) er[j] = epack[np + j];
        }
#pragma unroll
        for (int j = 0; j < 8; j++) {
            acc.x += us2f(gg[j].x) * ww[j];
            acc.y += us2f(gg[j].y) * ww[j];
            acc.z += us2f(gg[j].z) * ww[j];
            acc.w += us2f(gg[j].w) * ww[j];
            ssum += ww[j];
        }
    }
    for (; p < p1; p++) {
        int4 ev = epack[p];
        float wv = wext(ev, head);
        ushort4 hs = *(const ushort4*)&hb[(size_t)ev.x * HC + lane * 4];
        acc.x += us2f(hs.x) * wv;
        acc.y += us2f(hs.y) * wv;
        acc.z += us2f(hs.z) * wv;
        acc.w += us2f(hs.w) * wv;
        ssum += wv;
    }
    float inv = 1.f / ssum;
    ushort4 o;
    o.x = f2us(lrelu_act(acc.x * inv + ldin(bias, isbf, lane * 4 + 0)));
    o.y = f2us(lrelu_act(acc.y * inv + ldin(bias, isbf, lane * 4 + 1)));
    o.z = f2us(lrelu_act(acc.z * inv + ldin(bias, isbf, lane * 4 + 2)));
    o.w = f2us(lrelu_act(acc.w * inv + ldin(bias, isbf, lane * 4 + 3)));
    *(ushort4*)&outn[(size_t)n * HC + lane * 4] = o;
}

// ---------------- pooling: (graph, quarter) grid ----------------
__global__ __launch_bounds__(256) void k_pool2(const unsigned short* __restrict__ outn,
                                               const int* __restrict__ gs,
                                               float* __restrict__ sums) {
    int g = blockIdx.x, qq = blockIdx.y, t = threadIdx.x;
    int s = gs[g], e2 = gs[g + 1];
    int len = e2 - s;
    int r0 = s + (len * qq) / 4;
    int r1 = s + (len * (qq + 1)) / 4;
    float a0 = 0.f, a1 = 0.f, a2 = 0.f, a3 = 0.f;
    int r = r0;
    for (; r + 4 <= r1; r += 4) {
        a0 += us2f(outn[(size_t)(r + 0) * HC + t]);
        a1 += us2f(outn[(size_t)(r + 1) * HC + t]);
        a2 += us2f(outn[(size_t)(r + 2) * HC + t]);
        a3 += us2f(outn[(size_t)(r + 3) * HC + t]);
    }
    for (; r < r1; r++) a0 += us2f(outn[(size_t)r * HC + t]);
    float v = (a0 + a1) + (a2 + a3);
    if (r1 > r0) atomicAdd(&sums[(size_t)g * HC + t], v);
}

// ---------------- final FC (mean-divide folded in, dual-dtype out) ----------------
__global__ __launch_bounds__(256) void k_fc(const float* __restrict__ sums,
                                            const int* __restrict__ gs,
                                            const void* __restrict__ fw,
                                            const void* __restrict__ fb,
                                            void* __restrict__ out,
                                            const int* __restrict__ flag) {
    __shared__ float pl[HC];
    int isbf = *flag;
    int g = blockIdx.y;
    int o = blockIdx.x * 256 + threadIdx.x;
    int c = gs[g + 1] - gs[g];
    float inv = 1.f / (float)(c > 1 ? c : 1);
    pl[threadIdx.x] = sums[(size_t)g * HC + threadIdx.x] * inv;
    __syncthreads();
    float acc = ldin(fb, isbf, o);
#pragma unroll 8
    for (int k = 0; k < HC; k++) acc += pl[k] * ldin(fw, isbf, (size_t)k * NOUT + o);
    size_t oi = (size_t)g * NOUT + o;
    if (isbf) ((bf16*)out)[oi] = __float2bfloat16(acc);
    else      ((float*)out)[oi] = acc;
}

extern "C" void kernel_launch(void* const* d_in, const int* in_sizes, int n_in,
                              void* d_out, int out_size, void* d_ws, size_t ws_size,
                              hipStream_t stream) {
    const void* x     = d_in[0];
    const int*  ei    = (const int*)d_in[1];
    const int*  batch = (const int*)d_in[2];
    const void* lin_w = d_in[3];
    const void* att_s = d_in[4];
    const void* att_d = d_in[5];
    const void* bias  = d_in[6];
    const void* fc1w  = d_in[7];
    const void* fc1b  = d_in[8];

    char* p = (char*)d_ws;
    unsigned short* hb   = (unsigned short*)p; p += (size_t)N * HC * 2;   // 25.6 MB
    unsigned short* outn = (unsigned short*)p; p += (size_t)N * HC * 2;   // 25.6 MB
    float* a_src  = (float*)p; p += (size_t)N * H * 4;
    float* a_dst  = (float*)p; p += (size_t)N * H * 4;
    int* cnt      = (int*)p;   p += (size_t)N * 4;                        // cnt+sums zeroed together
    float* sums   = (float*)p; p += (size_t)G * HC * 4;
    int* off      = (int*)p;   p += (size_t)(N + 4) * 4;
    int* cur      = (int*)p;   p += (size_t)N * 4;
    int4* epack   = (int4*)p;  p += (size_t)E * 16;                       // 12.8 MB
    unsigned short* bswz = (unsigned short*)p; p += (size_t)160 * 64 * 8 * 2;
    int* bsum     = (int*)p;   p += 1024;
    int* gs       = (int*)p;   p += (size_t)(G + 4) * 4;
    int* flag     = (int*)p;   p += 16;

    const int NB = (N + 255) / 256;  // 196

    k_pre<<<NZB + 40 + 1, 256, 0, stream>>>((const unsigned short*)x, lin_w, batch,
                                            flag, cnt, bswz, gs);
    k_lin_mfma<<<MP / 64, 256, 0, stream>>>(x, bswz, att_s, att_d, hb, a_src, a_dst, flag);
    k_hist<<<(E + 255) / 256, 256, 0, stream>>>(ei + E, cnt);
    k_scan1<<<NB, 256, 0, stream>>>(cnt, bsum);
    k_scan23<<<NB, 256, 0, stream>>>(bsum, NB, cnt, off, cur);
    k_scatter<<<(E + 255) / 256, 256, 0, stream>>>(ei, a_src, a_dst, cur, epack);
    k_agg<<<(N + 3) / 4, 256, 0, stream>>>(hb, a_src, a_dst, off, epack, bias, outn, flag);
    k_pool2<<<dim3(G, 4), 256, 0, stream>>>(outn, gs, sums);
    k_fc<<<dim3(NOUT / 256, G), 256, 0, stream>>>(sums, gs, fc1w, fc1b, d_out, flag);
}